// Round 5
// baseline (34.851 us; speedup 1.0000x reference)
//
#include <hip/hip_runtime.h>
#include <math.h>

#define AMP_C 100.0f
#define NSD_SCALE_C 500.0f
#define NSD_SLOPE_C 10.0f
#define TWO_PI_C 6.2831853071795864769f

typedef float v4f __attribute__((ext_vector_type(4)));

#define ROWS_PER_BLOCK 512   // 256 threads x 2 rows
#define F4_PER_BLOCK   768   // 512 rows * 6 floats / 4
// per-wave: 128 rows = 192 float4 = 3 KB LDS region, fully wave-private

// Barrier-free LDS-staged streaming map. Each WAVE owns a contiguous
// 192-float4 LDS region, so no data crosses waves:
//   Phase 1: 3x global_load_lds_dwordx4 into the wave's own region.
//   Phase 2: s_waitcnt vmcnt(0) (wave-level, no s_barrier!), each lane
//            reads its 2 rows (ds_read_b128, stride-12 words -> 8 bank
//            groups, conflict-free), computes [v,a], writes back in place.
//   Phase 3: same-wave DS ordering (in-order pipeline) -> lane-contiguous
//            float4 stores. No __syncthreads anywhere: waves run free.
__global__ __launch_bounds__(256) void fused_kernel(
        const v4f* __restrict__ h4,
        v4f* __restrict__ o4,
        const float* __restrict__ hs,   // scalar views for tail
        float* __restrict__ os,
        const float* __restrict__ tp,
        const float* __restrict__ Mp,
        const float* __restrict__ Kp,
        const float* __restrict__ Cp,
        int nrows) {
    __shared__ float smem[ROWS_PER_BLOCK * 6];
    v4f* s4 = (v4f*)smem;

    const int tid  = threadIdx.x;
    const int lane = tid & 63;
    const int wv   = tid >> 6;          // wave id 0..3 (uniform per wave)
    const int wreg = 192 * wv;          // wave's float4 base in LDS
    const int row_base = blockIdx.x * ROWS_PER_BLOCK;
    const int rows_here = nrows - row_base;   // >= 1
    const bool full = (rows_here >= ROWS_PER_BLOCK);
    const size_t f4base = (size_t)blockIdx.x * F4_PER_BLOCK;

    // ---- phase 1: direct global->LDS DMA into wave-private region ----
    if (full) {
#pragma unroll
        for (int j = 0; j < 3; ++j) {
            __builtin_amdgcn_global_load_lds(
                (const uint32_t*)&h4[f4base + wreg + 64 * j + lane], // per-lane src
                (uint32_t*)&s4[wreg + 64 * j],                       // wave-uniform dest
                16, 0, 0);
        }
    }

    // ---- coefficient computation (uniform, overlaps DMA latency) ----
    float m00 = Mp[0], m01 = Mp[1], m02 = Mp[2];
    float m10 = Mp[3], m11 = Mp[4], m12 = Mp[5];
    float m20 = Mp[6], m21 = Mp[7], m22 = Mp[8];
    float det = m00 * (m11 * m22 - m12 * m21)
              - m01 * (m10 * m22 - m12 * m20)
              + m02 * (m10 * m21 - m11 * m20);
    float id = 1.0f / det;
    float inv[9];
    inv[0] =  (m11 * m22 - m12 * m21) * id;
    inv[1] = -(m01 * m22 - m02 * m21) * id;
    inv[2] =  (m01 * m12 - m02 * m11) * id;
    inv[3] = -(m10 * m22 - m12 * m20) * id;
    inv[4] =  (m00 * m22 - m02 * m20) * id;
    inv[5] = -(m00 * m12 - m02 * m10) * id;
    inv[6] =  (m10 * m21 - m11 * m20) * id;
    inv[7] = -(m00 * m21 - m01 * m20) * id;
    inv[8] =  (m00 * m11 - m01 * m10) * id;

    float A[9], Bc[9];
#pragma unroll
    for (int r = 0; r < 3; ++r) {
#pragma unroll
        for (int c = 0; c < 3; ++c) {
            float sK = 0.0f, sC = 0.0f;
#pragma unroll
            for (int k = 0; k < 3; ++k) {
                sK += inv[3 * r + k] * Kp[3 * k + c];
                sC += inv[3 * r + k] * Cp[3 * k + c];
            }
            A[3 * r + c]  = -sK;
            Bc[3 * r + c] = -sC;
        }
    }
    const float mi0 = inv[0], mi1 = inv[3], mi2 = inv[6];
    const float base = -AMP_C * sinf(TWO_PI_C * tp[0]);

    if (full) {
        // wave-level wait for our own 3 global_load_lds (no block barrier)
        asm volatile("s_waitcnt vmcnt(0)" ::: "memory");

        // ---- phase 2: 2 rows per lane from the wave's region ----
        v4f a0 = s4[wreg + 3 * lane + 0];
        v4f a1 = s4[wreg + 3 * lane + 1];
        v4f a2 = s4[wreg + 3 * lane + 2];
        float x[2][3] = {{a0[0], a0[1], a0[2]}, {a1[2], a1[3], a2[0]}};
        float v[2][3] = {{a0[3], a1[0], a1[1]}, {a2[1], a2[2], a2[3]}};
        float a[2][3];
#pragma unroll
        for (int r = 0; r < 2; ++r) {
            float f = -NSD_SCALE_C * tanhf(NSD_SLOPE_C * x[r][0]);
            a[r][0] = A[0] * x[r][0] + A[1] * x[r][1] + A[2] * x[r][2]
                    + Bc[0] * v[r][0] + Bc[1] * v[r][1] + Bc[2] * v[r][2]
                    + base + f * mi0;
            a[r][1] = A[3] * x[r][0] + A[4] * x[r][1] + A[5] * x[r][2]
                    + Bc[3] * v[r][0] + Bc[4] * v[r][1] + Bc[5] * v[r][2]
                    + base + f * mi1;
            a[r][2] = A[6] * x[r][0] + A[7] * x[r][1] + A[8] * x[r][2]
                    + Bc[6] * v[r][0] + Bc[7] * v[r][1] + Bc[8] * v[r][2]
                    + base + f * mi2;
        }
        v4f oa = {v[0][0], v[0][1], v[0][2], a[0][0]};
        v4f ob = {a[0][1], a[0][2], v[1][0], v[1][1]};
        v4f oc = {v[1][2], a[1][0], a[1][1], a[1][2]};
        s4[wreg + 3 * lane + 0] = oa;
        s4[wreg + 3 * lane + 1] = ob;
        s4[wreg + 3 * lane + 2] = oc;

        // compiler-ordering fence only; DS pipeline is in-order within a wave
        asm volatile("" ::: "memory");

        // ---- phase 3: lane-contiguous store from the wave's region ----
        o4[f4base + wreg + 0 * 64 + lane] = s4[wreg + 0 * 64 + lane];
        o4[f4base + wreg + 1 * 64 + lane] = s4[wreg + 1 * 64 + lane];
        o4[f4base + wreg + 2 * 64 + lane] = s4[wreg + 2 * 64 + lane];
    } else {
        // tail block: scalar per-row path (unused at B=4194304, kept for safety)
        for (int r = tid; r < rows_here; r += 256) {
            const size_t r0 = (size_t)(row_base + r) * 6;
            float x0 = hs[r0 + 0], x1 = hs[r0 + 1], x2 = hs[r0 + 2];
            float v0 = hs[r0 + 3], v1 = hs[r0 + 4], v2 = hs[r0 + 5];
            float f = -NSD_SCALE_C * tanhf(NSD_SLOPE_C * x0);
            float o3  = A[0]*x0 + A[1]*x1 + A[2]*x2 + Bc[0]*v0 + Bc[1]*v1 + Bc[2]*v2 + base + f*mi0;
            float o4v = A[3]*x0 + A[4]*x1 + A[5]*x2 + Bc[3]*v0 + Bc[4]*v1 + Bc[5]*v2 + base + f*mi1;
            float o5  = A[6]*x0 + A[7]*x1 + A[8]*x2 + Bc[6]*v0 + Bc[7]*v1 + Bc[8]*v2 + base + f*mi2;
            os[r0 + 0] = v0; os[r0 + 1] = v1; os[r0 + 2] = v2;
            os[r0 + 3] = o3; os[r0 + 4] = o4v; os[r0 + 5] = o5;
        }
    }
}

extern "C" void kernel_launch(void* const* d_in, const int* in_sizes, int n_in,
                              void* d_out, int out_size, void* d_ws, size_t ws_size,
                              hipStream_t stream) {
    const float* t = (const float*)d_in[0];
    const float* h = (const float*)d_in[1];
    const float* M = (const float*)d_in[2];
    const float* K = (const float*)d_in[3];
    const float* C = (const float*)d_in[4];
    float* out = (float*)d_out;

    const int nrows = in_sizes[1] / 6;
    const int grid = (nrows + ROWS_PER_BLOCK - 1) / ROWS_PER_BLOCK;

    fused_kernel<<<grid, 256, 0, stream>>>(
        (const v4f*)h, (v4f*)out, h, out, t, M, K, C, nrows);
}